// Round 6
// baseline (186.973 us; speedup 1.0000x reference)
//
#include <hip/hip_runtime.h>

// MultiHashEncoding: 2-level dense grid trilinear interpolation.
// Level 0: emb0 [16,136,241,16], Level 1: emb1 [9,69,121,16]; out [N,32] f32.
//
// Reference semantics (bit-exact corners): corner = floor(coords + OFFSET)
// with the f32 add BEFORE floor; corner clipped to [0, dim-1]; weight from the
// CLIPPED corner. Weights are separable per-dim -> factor once, multiply per
// corner (rounding-order diff vs ref is ~1e-7, threshold 8.1e-2).
//
// Parallelization: 4 lanes = 1 point; lane d owns dims 4d..4d+3 (float4).
// Per corner: 4 lanes x 16B contiguous = ONE 64B transaction (same minimal
// transaction count as round 5's 16-lane variant) with 4x less redundant
// VALU. Round-5 evidence: VALUBusy 50% was the serializing component.

typedef float floatx4 __attribute__((ext_vector_type(4)));

template<int T, int H, int W>
__device__ __forceinline__ void level_setup(float px, float py, float pz, int dbase,
                                            int* __restrict__ off,   // [8]
                                            float* __restrict__ w) { // [8]
    const float cx = px * (float)(T - 1);
    const float cy = py * (float)(H - 1);
    const float cz = pz * (float)(W - 1);
    // floor(c + offset) with f32 add BEFORE floor (bit-exact vs reference)
    float gx[2] = { floorf(cx), floorf(cx + 1.0f) };
    float gy[2] = { floorf(cy), floorf(cy + 1.0f) };
    float gz[2] = { floorf(cz), floorf(cz + 1.0f) };
    float wx[2], wy[2], wz[2];
    int   xo[2], yo[2], zo[2];
#pragma unroll
    for (int b = 0; b < 2; ++b) {
        gx[b] = fminf(fmaxf(gx[b], 0.0f), (float)(T - 1));
        gy[b] = fminf(fmaxf(gy[b], 0.0f), (float)(H - 1));
        gz[b] = fminf(fmaxf(gz[b], 0.0f), (float)(W - 1));
        wx[b] = 1.0f - fabsf(gx[b] - cx);
        wy[b] = 1.0f - fabsf(gy[b] - cy);
        wz[b] = 1.0f - fabsf(gz[b] - cz);
        xo[b] = (int)gx[b] * (H * W * 16);
        yo[b] = (int)gy[b] * (W * 16);
        zo[b] = (int)gz[b] * 16 + dbase;
    }
    float wyz[4];
    int   yzo[4];
#pragma unroll
    for (int j = 0; j < 2; ++j)
#pragma unroll
        for (int k = 0; k < 2; ++k) {
            wyz[2 * j + k] = wy[j] * wz[k];
            yzo[2 * j + k] = yo[j] + zo[k];
        }
#pragma unroll
    for (int c = 0; c < 8; ++c) {
        const int i = (c >> 2) & 1, jk = c & 3;
        w[c]   = wx[i] * wyz[jk];
        off[c] = xo[i] + yzo[jk];
    }
}

__global__ __launch_bounds__(256)
void MultiHashEncoding_79860621902018_kernel(const float* __restrict__ pts,
                                             const float* __restrict__ emb0,
                                             const float* __restrict__ emb1,
                                             float* __restrict__ out, int n) {
    const int g = blockIdx.x * blockDim.x + threadIdx.x;
    const int p = g >> 2;        // point index
    const int d = (g & 3) * 4;   // first embedding dim owned by this lane
    if (p >= n) return;

    const size_t base = (size_t)p * 3;
    const float px = pts[base + 0];
    const float py = pts[base + 1];
    const float pz = pts[base + 2];

    int   o0[8], o1[8];
    float w0[8], w1[8];
    level_setup<16, 136, 241>(px, py, pz, d, o0, w0);
    level_setup<9, 69, 121>(px, py, pz, d, o1, w1);

    // Issue all 16 independent float4 gathers before any use.
    floatx4 v0[8], v1[8];
#pragma unroll
    for (int c = 0; c < 8; ++c) v0[c] = *(const floatx4*)(emb0 + o0[c]);
#pragma unroll
    for (int c = 0; c < 8; ++c) v1[c] = *(const floatx4*)(emb1 + o1[c]);

    floatx4 a0 = {0.f, 0.f, 0.f, 0.f}, a1 = {0.f, 0.f, 0.f, 0.f};
#pragma unroll
    for (int c = 0; c < 8; ++c) {
        a0 += w0[c] * v0[c];
        a1 += w1[c] * v1[c];
    }

    // Streaming coalesced writes (keep L2 for the embedding tables).
    float* row = out + (size_t)p * 32 + d;
    __builtin_nontemporal_store(a0, (floatx4*)row);
    __builtin_nontemporal_store(a1, (floatx4*)(row + 16));
}

extern "C" void kernel_launch(void* const* d_in, const int* in_sizes, int n_in,
                              void* d_out, int out_size, void* d_ws, size_t ws_size,
                              hipStream_t stream) {
    const float* pts  = (const float*)d_in[0];
    const float* emb0 = (const float*)d_in[1];
    const float* emb1 = (const float*)d_in[2];
    float* out = (float*)d_out;
    const int n = in_sizes[0] / 3;

    const int block = 256;
    const long long total = (long long)n * 4;
    const int grid = (int)((total + block - 1) / block);
    MultiHashEncoding_79860621902018_kernel<<<grid, block, 0, stream>>>(
        pts, emb0, emb1, out, n);
}